// Round 5
// baseline (477.557 us; speedup 1.0000x reference)
//
#include <hip/hip_runtime.h>
#include <hip/hip_bf16.h>
#include <math.h>

// Problem constants (N,C,H,W) = (16,128,128,128)
#define CN      128
#define HWN     16384
#define NBATCH  16
#define PLANE   (CN * HWN)
#define TSTRIDE ((size_t)NBATCH * PLANE)   // elems per tensor in kqv buf

typedef __attribute__((ext_vector_type(8))) short  short8;   // 8 bf16 = 4 VGPR
typedef __attribute__((ext_vector_type(4))) float  float4v;  // MFMA C/D

__device__ __forceinline__ unsigned short f2b(float f) {
    __hip_bfloat16 h = __float2bfloat16(f);
    return *reinterpret_cast<unsigned short*>(&h);
}
__device__ __forceinline__ unsigned packbf(float lo, float hi) {
    return (unsigned)f2b(lo) | ((unsigned)f2b(hi) << 16);
}

// ---------------------------------------------------------------------------
// Prep: weights -> bf16 wbf[o'][c] (o' = tensor*128+o, c contiguous), biases
// -> f32 bias[384].
// ---------------------------------------------------------------------------
__global__ void prep_kernel(const float* __restrict__ wk, const float* __restrict__ bk,
                            const float* __restrict__ wq, const float* __restrict__ bq,
                            const float* __restrict__ wv, const float* __restrict__ bv,
                            unsigned short* __restrict__ wbf, float* __restrict__ bias)
{
    int i = blockIdx.x * 256 + threadIdx.x;   // 0..49151
    int tensor = i >> 14, oc = i & 16383;
    const float* w = tensor == 0 ? wk : (tensor == 1 ? wq : wv);
    wbf[i] = f2b(w[oc]);
    if (i < 384) {
        const float* b = i < 128 ? bk : (i < 256 ? bq : bv);
        bias[i] = b[i & 127];
    }
}

// ---------------------------------------------------------------------------
// Unified conv (phase A): ONE x staging per (h:16 x w:16) spatial tile serves
// all 3 tensors. LDS tile Xl[s][c] (s = h*16+w, 64 KiB, XOR-swizzled cols).
//   TRANS (K,Q): M-order w*16+h -> D rows = consecutive h -> [o][w][h] stores
//   natural (V): M-order h*16+w -> D rows = consecutive w -> [o][h][w] stores
// Round-5 changes:
//   * 512-thread blocks (8 waves): 2 blocks/CU x 8 waves = 16 waves/CU (was 8)
//   * clique XCD swizzle: the 16 blocks of a 64x64 super-tile (writers of
//     each 128 B kqv line, both layouts) land on ONE XCD, 8 dispatch slots
//     apart -> L2 merges 32 B store sectors into full-line evictions.
// ---------------------------------------------------------------------------
__device__ __forceinline__ int swzkey(int s) { return ((s ^ (s >> 4)) & 7) << 2; }

template<bool TRANS>
__device__ __forceinline__ void conv_phase(
    const unsigned* Xl, const unsigned short* __restrict__ wbf,
    const float* __restrict__ bias, unsigned short* kqv_t,
    int tens, int h0, int w0, int wv, int l15, int quad)
{
    #pragma unroll
    for (int og = 0; og < 2; ++og) {
        float bs[4];
        #pragma unroll
        for (int ni = 0; ni < 4; ++ni)
            bs[ni] = bias[tens * 128 + og * 64 + ni * 16 + l15];

        float4v acc[2][4];
        #pragma unroll
        for (int mi = 0; mi < 2; ++mi)
            #pragma unroll
            for (int ni = 0; ni < 4; ++ni)
                acc[mi][ni] = (float4v){bs[ni], bs[ni], bs[ni], bs[ni]};

        #pragma unroll
        for (int k = 0; k < 4; ++k) {
            short8 afr[2];
            #pragma unroll
            for (int mi = 0; mi < 2; ++mi) {
                const int mt = wv * 2 + mi;
                const int s  = TRANS ? (l15 * 16 + mt) : (mt * 16 + l15);
                afr[mi] = *(const short8*)&Xl[s * 64 + ((k * 16 + quad * 4) ^ swzkey(s))];
            }
            #pragma unroll
            for (int ni = 0; ni < 4; ++ni) {
                const short8 wfr = *(const short8*)
                    &wbf[(size_t)(tens * 128 + og * 64 + ni * 16 + l15) * CN + quad * 8 + k * 32];
                #pragma unroll
                for (int mi = 0; mi < 2; ++mi)
                    acc[mi][ni] = __builtin_amdgcn_mfma_f32_16x16x32_bf16(afr[mi], wfr, acc[mi][ni], 0, 0, 0);
            }
        }

        #pragma unroll
        for (int ni = 0; ni < 4; ++ni) {
            const int o = og * 64 + ni * 16 + l15;
            unsigned short* dst0 = kqv_t + (size_t)o * HWN;
            #pragma unroll
            for (int mi = 0; mi < 2; ++mi) {
                const int mt  = wv * 2 + mi;
                const int idx = TRANS ? ((w0 + mt) * 128 + h0 + quad * 4)
                                      : ((h0 + mt) * 128 + w0 + quad * 4);
                uint2 u;
                u.x = packbf(acc[mi][ni][0], acc[mi][ni][1]);
                u.y = packbf(acc[mi][ni][2], acc[mi][ni][3]);
                *(uint2*)(dst0 + idx) = u;
            }
        }
    }
}

__global__ __launch_bounds__(512) void conv_kernel(
    const float* __restrict__ x, const unsigned short* __restrict__ wbf,
    const float* __restrict__ bias, unsigned short* __restrict__ kqv)
{
    __shared__ unsigned Xl[256 * 64];   // [s][c/2] swizzled, 64 KiB -> 2 blocks/CU

    // ---- clique XCD swizzle: d -> (supertile st, member) ----
    // st = (d>>7)*8 + (d&7)  (0..63): n = st>>2, h-half = (st>>1)&1, w-half = st&1
    // member = (d>>3)&15: hi = member>>2, wi = member&3
    // All 16 members of a supertile: same d mod 8 (same XCD), spaced 8 apart.
    const int d      = blockIdx.x;
    const int st     = ((d >> 7) << 3) | (d & 7);
    const int member = (d >> 3) & 15;
    const int n  = st >> 2;
    const int h0 = ((((st >> 1) & 1) << 2) | (member >> 2)) << 4;
    const int w0 = (((st & 1) << 2) | (member & 3)) << 4;

    const int th = threadIdx.x, lane = th & 63, wv = th >> 6;   // wv 0..7
    const int l15 = lane & 15, quad = lane >> 4;

    // ---- stage x[c][h0:+16][w0:+16] -> Xl (bf16, swizzled) ----
    // lanes = 16 h-rows x 4 w-quads: 16 x 64 B coalesced per instruction.
    {
        const int sh = lane & 15, swq = lane >> 4;
        const float* xp = x + (size_t)n * PLANE + (h0 + sh) * 128 + w0 + swq * 4;
        #pragma unroll
        for (int b = 0; b < 2; ++b) {
            const int cb = wv * 16 + b * 8;     // 8 channels per iter
            float v[8][4];
            #pragma unroll
            for (int j = 0; j < 8; ++j)
                *(float4*)v[j] = *(const float4*)(xp + (size_t)(cb + j) * HWN);
            #pragma unroll
            for (int wi = 0; wi < 4; ++wi) {
                const int s = sh * 16 + swq * 4 + wi;
                uint4 u;
                u.x = packbf(v[0][wi], v[1][wi]); u.y = packbf(v[2][wi], v[3][wi]);
                u.z = packbf(v[4][wi], v[5][wi]); u.w = packbf(v[6][wi], v[7][wi]);
                *(uint4*)&Xl[s * 64 + ((cb / 2) ^ swzkey(s))] = u;
            }
        }
    }
    __syncthreads();

    unsigned short* base = kqv + ((size_t)n * CN) * HWN;
    conv_phase<true >(Xl, wbf, bias, base,               0, h0, w0, wv, l15, quad);  // K
    conv_phase<true >(Xl, wbf, bias, base + TSTRIDE,     1, h0, w0, wv, l15, quad);  // Q
    conv_phase<false>(Xl, wbf, bias, base + 2 * TSTRIDE, 2, h0, w0, wv, l15, quad);  // V
}

// ---------------------------------------------------------------------------
// Phase B: per (n,o) block (256 thr), ZERO barriers, ZERO K/Q staging:
//   GEMM1: S^T[v][w] = sum_h Q'[v][h]*K'[w][h] — fragments straight from
//          global transposed planes (16 B/lane, 64 B-coalesced segments).
//   softmax over w in registers; attn^T bf16 -> LDS (wave-private rows).
//   GEMM2: A = attn^T (own rows), B = V rows [h][w] from global.
// LDS 34 KiB (At only). UNCHANGED from round 2 (verified).
// ---------------------------------------------------------------------------
__global__ __launch_bounds__(256) void attn_kernel(
    const unsigned short* __restrict__ kqv, const float* __restrict__ x,
    const float* __restrict__ gamma, float* __restrict__ out)
{
    __shared__ unsigned short At[128 * 136];   // attn^T [v][w], 34 KiB

    const int no = blockIdx.x;
    const unsigned short* Kg = kqv + (size_t)no * HWN;            // [w][h]
    const unsigned short* Qg = Kg + TSTRIDE;                      // [v][h]
    const unsigned short* Vg = Kg + 2 * TSTRIDE;                  // [h][w]

    const int t = threadIdx.x, lane = t & 63, wv = t >> 6;
    const int l15 = lane & 15, quad = lane >> 4;
    const int v0 = wv * 32;

    // ---- GEMM1: wave handles v-strip of 32 (2 m-tiles x 8 n-tiles x 4 k) ----
    float4v acc1[2][8];
    #pragma unroll
    for (int mt = 0; mt < 2; ++mt)
        #pragma unroll
        for (int nt = 0; nt < 8; ++nt) acc1[mt][nt] = (float4v){0.f, 0.f, 0.f, 0.f};

    {
        short8 afr[2][4];
        #pragma unroll
        for (int mt = 0; mt < 2; ++mt)
            #pragma unroll
            for (int k = 0; k < 4; ++k)
                afr[mt][k] = *(const short8*)&Qg[(v0 + mt * 16 + l15) * 128 + quad * 8 + k * 32];
        #pragma unroll
        for (int nt = 0; nt < 8; ++nt) {
            short8 bfr[4];
            #pragma unroll
            for (int k = 0; k < 4; ++k)
                bfr[k] = *(const short8*)&Kg[(nt * 16 + l15) * 128 + quad * 8 + k * 32];
            #pragma unroll
            for (int mt = 0; mt < 2; ++mt)
                #pragma unroll
                for (int k = 0; k < 4; ++k)
                    acc1[mt][nt] = __builtin_amdgcn_mfma_f32_16x16x32_bf16(afr[mt][k], bfr[k], acc1[mt][nt], 0, 0, 0);
        }
    }

    // ---- softmax over w (rows of S^T), in registers ----
    const float sc = 0.08838834764831845f;   // 1/sqrt(128)
    #pragma unroll
    for (int mt = 0; mt < 2; ++mt)
        #pragma unroll
        for (int r = 0; r < 4; ++r) {
            float m = -INFINITY;
            #pragma unroll
            for (int nt = 0; nt < 8; ++nt) {
                acc1[mt][nt][r] *= sc;
                m = fmaxf(m, acc1[mt][nt][r]);
            }
            #pragma unroll
            for (int d = 1; d < 16; d <<= 1) m = fmaxf(m, __shfl_xor(m, d, 64));
            float s = 0.f;
            #pragma unroll
            for (int nt = 0; nt < 8; ++nt) {
                const float e = __expf(acc1[mt][nt][r] - m);
                acc1[mt][nt][r] = e;
                s += e;
            }
            #pragma unroll
            for (int d = 1; d < 16; d <<= 1) s += __shfl_xor(s, d, 64);
            const float inv = 1.0f / s;
            const int v = v0 + mt * 16 + quad * 4 + r;
            #pragma unroll
            for (int nt = 0; nt < 8; ++nt)
                At[v * 136 + nt * 16 + l15] = f2b(acc1[mt][nt][r] * inv);
        }
    // no barrier: GEMM2 reads only this wave's own At rows [v0, v0+32);
    // per-wave DS ops are in order.

    // ---- GEMM2: A = At (M = v, own strip), B = V (N = h, k = w) ----
    float4v acc2[2][8];
    #pragma unroll
    for (int mt = 0; mt < 2; ++mt)
        #pragma unroll
        for (int nt = 0; nt < 8; ++nt) acc2[mt][nt] = (float4v){0.f, 0.f, 0.f, 0.f};

    {
        short8 pfr[2][4];
        #pragma unroll
        for (int mt = 0; mt < 2; ++mt)
            #pragma unroll
            for (int k = 0; k < 4; ++k)
                pfr[mt][k] = *(const short8*)&At[(v0 + mt * 16 + l15) * 136 + quad * 8 + k * 32];
        #pragma unroll
        for (int nt = 0; nt < 8; ++nt) {
            short8 vfr[4];
            #pragma unroll
            for (int k = 0; k < 4; ++k)
                vfr[k] = *(const short8*)&Vg[(nt * 16 + l15) * 128 + quad * 8 + k * 32];
            #pragma unroll
            for (int mt = 0; mt < 2; ++mt)
                #pragma unroll
                for (int k = 0; k < 4; ++k)
                    acc2[mt][nt] = __builtin_amdgcn_mfma_f32_16x16x32_bf16(pfr[mt][k], vfr[k], acc2[mt][nt], 0, 0, 0);
        }
    }

    // ---- epilogue: out = gamma*O + x, float4 (4 consecutive v per lane) ----
    const float g = gamma[0];
    const float* xp = x + (size_t)no * HWN;
    float*       op = out + (size_t)no * HWN;
    #pragma unroll
    for (int mt = 0; mt < 2; ++mt)
        #pragma unroll
        for (int nt = 0; nt < 8; ++nt) {
            const int h    = nt * 16 + l15;
            const int vcol = v0 + mt * 16 + quad * 4;
            const int idx  = h * 128 + vcol;
            float4 xv = *(const float4*)(xp + idx);
            float4 ov;
            ov.x = fmaf(g, acc2[mt][nt][0], xv.x);
            ov.y = fmaf(g, acc2[mt][nt][1], xv.y);
            ov.z = fmaf(g, acc2[mt][nt][2], xv.z);
            ov.w = fmaf(g, acc2[mt][nt][3], xv.w);
            *(float4*)(op + idx) = ov;
        }
}

// ---------------------------------------------------------------------------
extern "C" void kernel_launch(void* const* d_in, const int* in_sizes, int n_in,
                              void* d_out, int out_size, void* d_ws, size_t ws_size,
                              hipStream_t stream) {
    const float* x     = (const float*)d_in[0];
    const float* wk    = (const float*)d_in[1];
    const float* bk    = (const float*)d_in[2];
    const float* wq    = (const float*)d_in[3];
    const float* bq    = (const float*)d_in[4];
    const float* wv    = (const float*)d_in[5];
    const float* bv    = (const float*)d_in[6];
    const float* gamma = (const float*)d_in[7];
    float* out = (float*)d_out;

    // ws: wbf bf16 (96 KiB) | bias f32 @192 KiB | kqv bf16 @256 KiB (192 MiB)
    unsigned short* wbf  = (unsigned short*)d_ws;
    float*          bias = (float*)((char*)d_ws + (192 << 10));
    unsigned short* kqv  = (unsigned short*)((char*)d_ws + (256 << 10));

    prep_kernel<<<192, 256, 0, stream>>>(wk, bk, wq, bq, wv, bv, wbf, bias);
    conv_kernel<<<1024, 512, 0, stream>>>(x, wbf, bias, kqv);
    attn_kernel<<<NBATCH * CN, 256, 0, stream>>>(kqv, x, gamma, out);
}